// Round 6
// baseline (237.030 us; speedup 1.0000x reference)
//
#include <hip/hip_runtime.h>
#include <hip/hip_bf16.h>

#define N_NODES 200000
#define KDIM 27
#define TAPS_PAD 28
#define C_IN 32
#define C_OUT 32
#define REG_CNT 4
#define REG_SIZE 50000            // 50000 nodes * 64B = 3.2 MB < 4 MB L2/XCD
#define NTILES 6250               // 32-node tiles, exact
#define CONV_BLOCKS 3125          // 800000 threads, 8 floats each
#define PACK_BLOCKS 112           // 28*2*64*8 = 28672 threads
#define TRANS_BLOCKS 782          // 200000 nodes / 256
#define MAIN_BLOCKS 1563          // 4 waves/block, 6252 waves (2 idle)

typedef __bf16 bf16x8 __attribute__((ext_vector_type(8)));
typedef float floatx4 __attribute__((ext_vector_type(4)));
typedef float float4_t __attribute__((ext_vector_type(4)));

__device__ inline bf16x8 zero_bf16x8() {
    bf16x8 z;
#pragma unroll
    for (int i = 0; i < 8; ++i) z[i] = (__bf16)0.0f;
    return z;
}

// Aux: 3 arms.
//  [0, CONV):            data fp32 [N][32] -> bf16 [N][32] (64B rows)
//  [CONV, CONV+PACK):    weights -> B-frag pack, 28 taps (tap 27 zero)
//  [CONV+PACK, +TRANS):  neigh [N][27] int32 -> neighT [28][N] (row 27 = -1)
__global__ __launch_bounds__(256) void aux_kernel(
    const float* __restrict__ src, __bf16* __restrict__ dst,
    const float* __restrict__ w, __bf16* __restrict__ wp,
    const int* __restrict__ neigh, int* __restrict__ neighT) {
    if (blockIdx.x < CONV_BLOCKS) {
        int i = blockIdx.x * 256 + threadIdx.x;     // < 800000 exact
        const float4_t* s = (const float4_t*)src;
        float4_t v0 = s[2 * i];
        float4_t v1 = s[2 * i + 1];
        bf16x8 o;
        o[0] = (__bf16)v0[0]; o[1] = (__bf16)v0[1];
        o[2] = (__bf16)v0[2]; o[3] = (__bf16)v0[3];
        o[4] = (__bf16)v1[0]; o[5] = (__bf16)v1[1];
        o[6] = (__bf16)v1[2]; o[7] = (__bf16)v1[3];
        ((bf16x8*)dst)[i] = o;
    } else if (blockIdx.x < CONV_BLOCKS + PACK_BLOCKS) {
        int id = (blockIdx.x - CONV_BLOCKS) * 256 + threadIdx.x;
        if (id >= TAPS_PAD * 2 * 64 * 8) return;
        int j = id & 7;
        int lane = (id >> 3) & 63;
        int g = id >> 9;              // 0..55
        int tt = g & 1;
        int kk = g >> 1;              // 0..27
        int c = ((lane >> 4) << 3) + j;
        int o = tt * 16 + (lane & 15);
        wp[id] = (kk < KDIM) ? (__bf16)w[((size_t)kk * C_IN + c) * C_OUT + o] : (__bf16)0.0f;
    } else {
        int n = (blockIdx.x - CONV_BLOCKS - PACK_BLOCKS) * 256 + threadIdx.x;
        if (n >= N_NODES) return;
#pragma unroll
        for (int kk = 0; kk < KDIM; ++kk)
            neighT[(size_t)kk * N_NODES + n] = neigh[(size_t)n * KDIM + kk];
        neighT[(size_t)KDIM * N_NODES + n] = -1;   // pad tap 27
    }
}

// Phase kernel: gathers restricted to region rphase; accumulators RMW through out (fp32).
// Wave = 32 nodes (two 16-row m-halves). A-frag: A[m=r16][k=q*8+j] — lane (r16,q) loads
// data[idx]*64B + q*16B; 4 lanes fully consume each 64B row line.
// neighT idx block-load: lane holds tap 2g+(lane>>5), row lane&31 — NT, single-touch,
// coalesced; redistributed per tap via shfl. out RMW loads/stores NT.
// => only region data lines allocate in L2 -> region stays resident.
__global__ __launch_bounds__(256) void phase_kernel(
    const int* __restrict__ neighT, const __bf16* __restrict__ data_bf,
    const __bf16* __restrict__ wpack, float* __restrict__ out, int rphase) {
    int tid  = threadIdx.x;
    int lane = tid & 63;
    int wave_id = blockIdx.x * 4 + (tid >> 6);
    if (wave_id >= NTILES) return;
    int base = wave_id * 32;
    int r16 = lane & 15;
    int q   = lane >> 4;
    int cb  = q << 3;
    unsigned lo = (unsigned)(rphase * REG_SIZE);

    // Idx block-load: 14 NT loads, each wave reads 2 taps x 32 rows contiguous.
    int row_l   = lane & 31;
    int tap_sel = lane >> 5;
    int idxv[14];
#pragma unroll
    for (int g = 0; g < 14; ++g)
        idxv[g] = __builtin_nontemporal_load(
            neighT + (size_t)(2 * g + tap_sel) * N_NODES + base + row_l);

    // Accumulators: zero on phase 0, else NT-load partials from out.
    floatx4 acc00, acc01, acc10, acc11;
    if (rphase == 0) {
        acc00 = (floatx4){0.f, 0.f, 0.f, 0.f};
        acc01 = (floatx4){0.f, 0.f, 0.f, 0.f};
        acc10 = (floatx4){0.f, 0.f, 0.f, 0.f};
        acc11 = (floatx4){0.f, 0.f, 0.f, 0.f};
    } else {
#pragma unroll
        for (int rr = 0; rr < 4; ++rr) {
            int row = q * 4 + rr;
            const float* p0 = out + (size_t)(base + row) * C_OUT + r16;
            const float* p1 = out + (size_t)(base + 16 + row) * C_OUT + r16;
            acc00[rr] = __builtin_nontemporal_load(p0);
            acc01[rr] = __builtin_nontemporal_load(p0 + 16);
            acc10[rr] = __builtin_nontemporal_load(p1);
            acc11[rr] = __builtin_nontemporal_load(p1 + 16);
        }
    }

    const bf16x8* wp8 = (const bf16x8*)wpack;
    int ia_[2], ib_[2];
    bf16x8 A0_[2], A1_[2];

#define PREP(kk)                                                            \
    {                                                                       \
        int p_ = (kk) & 1;                                                  \
        int srcA_ = (((kk) & 1) << 5) + r16;                                \
        ia_[p_] = __shfl(idxv[(kk) >> 1], srcA_, 64);                       \
        ib_[p_] = __shfl(idxv[(kk) >> 1], srcA_ + 16, 64);                  \
    }
#define GATHER(kk)                                                          \
    {                                                                       \
        int p_ = (kk) & 1;                                                  \
        bf16x8 x_ = zero_bf16x8();                                          \
        bf16x8 y_ = zero_bf16x8();                                          \
        if ((unsigned)ia_[p_] - lo < (unsigned)REG_SIZE)                    \
            x_ = *(const bf16x8*)(data_bf + ((size_t)(unsigned)ia_[p_] << 5) + cb); \
        if ((unsigned)ib_[p_] - lo < (unsigned)REG_SIZE)                    \
            y_ = *(const bf16x8*)(data_bf + ((size_t)(unsigned)ib_[p_] << 5) + cb); \
        A0_[p_] = x_;                                                       \
        A1_[p_] = y_;                                                       \
    }
#define DO_MFMA(kk)                                                         \
    {                                                                       \
        int p_ = (kk) & 1;                                                  \
        bf16x8 b0_ = wp8[((kk) * 2 + 0) * 64 + lane];                       \
        bf16x8 b1_ = wp8[((kk) * 2 + 1) * 64 + lane];                       \
        acc00 = __builtin_amdgcn_mfma_f32_16x16x32_bf16(A0_[p_], b0_, acc00, 0, 0, 0); \
        acc01 = __builtin_amdgcn_mfma_f32_16x16x32_bf16(A0_[p_], b1_, acc01, 0, 0, 0); \
        acc10 = __builtin_amdgcn_mfma_f32_16x16x32_bf16(A1_[p_], b0_, acc10, 0, 0, 0); \
        acc11 = __builtin_amdgcn_mfma_f32_16x16x32_bf16(A1_[p_], b1_, acc11, 0, 0, 0); \
    }

    PREP(0); PREP(1);
    GATHER(0);
#pragma unroll
    for (int kk = 0; kk < KDIM; ++kk) {
        if (kk + 2 < KDIM) PREP(kk + 2);
        if (kk + 1 < KDIM) GATHER(kk + 1);
        DO_MFMA(kk);
    }
#undef PREP
#undef GATHER
#undef DO_MFMA

    // NT store partials/final. C/D: row = q*4 + rr, col = r16.
#pragma unroll
    for (int rr = 0; rr < 4; ++rr) {
        int row = q * 4 + rr;
        float* p0 = out + (size_t)(base + row) * C_OUT + r16;
        float* p1 = out + (size_t)(base + 16 + row) * C_OUT + r16;
        __builtin_nontemporal_store(acc00[rr], p0);
        __builtin_nontemporal_store(acc01[rr], p0 + 16);
        __builtin_nontemporal_store(acc10[rr], p1);
        __builtin_nontemporal_store(acc11[rr], p1 + 16);
    }
}

extern "C" void kernel_launch(void* const* d_in, const int* in_sizes, int n_in,
                              void* d_out, int out_size, void* d_ws, size_t ws_size,
                              hipStream_t stream) {
    const float* data    = (const float*)d_in[0];   // [N, C_IN] fp32
    const float* weights = (const float*)d_in[1];   // [K, C_IN, C_OUT] fp32
    const int*   neigh   = (const int*)d_in[2];     // [N, K] int32
    float*       out     = (float*)d_out;           // [N, C_OUT] fp32

    char* ws = (char*)d_ws;
    __bf16* data_bf = (__bf16*)ws;                               // 12.8 MB
    __bf16* wpack   = (__bf16*)(ws + 12800000);                  // 57 KB
    int*    neighT  = (int*)(ws + 12800000 + 57344);             // 22.4 MB

    hipLaunchKernelGGL(aux_kernel, dim3(CONV_BLOCKS + PACK_BLOCKS + TRANS_BLOCKS),
                       dim3(256), 0, stream, data, data_bf, weights, wpack, neigh, neighT);

    for (int r = 0; r < REG_CNT; ++r)
        hipLaunchKernelGGL(phase_kernel, dim3(MAIN_BLOCKS), dim3(256), 0, stream,
                           neighT, data_bf, wpack, out, r);
}